// Round 8
// baseline (260.361 us; speedup 1.0000x reference)
//
#include <hip/hip_runtime.h>
#include <cstdint>
#include <math.h>

#define B 8
#define L 2048
#define D 256
#define H 128

typedef __attribute__((ext_vector_type(8))) _Float16 half8;
typedef __attribute__((ext_vector_type(4))) _Float16 half4t;
typedef __attribute__((ext_vector_type(2))) _Float16 half2v;
typedef __attribute__((ext_vector_type(4))) float f32x4;
typedef unsigned short ushort;
typedef unsigned int uint;

// Layouts:
//  pq/pk (B*L*H fp16) packed MFMA-frag blocks: block=(grow/16)*4+h/32,
//     elem=((h>>3)&3)*128+(grow&15)*8+(h&7)   [proven R4-R6]
//  vt (B*L*D fp16): block=((b*L+key)/32)*16+d/16, elem=((key&31)>>3)*128+(d&15)*8+(key&7)
// Fused attention (R7/R8): no S materialization; D split across BLOCKS:
//   blockIdx.z = z*2 + dh; each block computes 64 rows x 128 d-cols.
//   z=0: rows=q, inner=keys,  S^T = pk·pq^T, V=vt1, bias=fb1 (over keys)
//   z=1: rows=k, inner=query, S^T = pq·pk^T, V=vt2, bias=fb2 (over queries)
//   QK^T + softmax duplicated across the 2 dh-blocks (cheap); V staging,
//   PV MFMA, LDS and acc halve -> 1024 blocks = 4/CU = 4 waves/SIMD.

// ---------------------------------------------------------------------------
// prep: masks -> float bias (0 / -inf), W -> fp16 fragment blocks.
// ---------------------------------------------------------------------------
__global__ void prep_kernel(const void* __restrict__ raw0,
                            const void* __restrict__ raw1,
                            const float* __restrict__ Wq,
                            const float* __restrict__ Wk,
                            float* __restrict__ fb1,
                            float* __restrict__ fb2,
                            _Float16* __restrict__ Wf) {
    const int t = threadIdx.x;
    const int z = blockIdx.y;
    {
        const void* raw = z ? raw1 : raw0;
        float* outb = z ? fb2 : fb1;
        const uint* wd = (const uint*)raw;
        __shared__ int flag;
        if (t == 0) flag = 0;
        __syncthreads();
        if (wd[t] > 1u) flag = 1;   // byte-bool layout iff some word >1
        __syncthreads();
        const int base = blockIdx.x * 1024;
        if (flag) {
            const uint8_t* by = (const uint8_t*)raw;
#pragma unroll
            for (int j = 0; j < 4; ++j) {
                int i = base + t + 256 * j;
                outb[i] = by[i] ? -INFINITY : 0.f;
            }
        } else {
#pragma unroll
            for (int j = 0; j < 4; ++j) {
                int i = base + t + 256 * j;
                outb[i] = wd[i] ? -INFINITY : 0.f;
            }
        }
    }
    {
        const float* Wsrc = z ? Wk : Wq;
        const int chunk = blockIdx.x * 256 + t;   // 0..4095
        const int h = chunk >> 5;
        const int d0 = (chunk & 31) * 8;
        float4 v0 = *(const float4*)(Wsrc + (size_t)h * 256 + d0);
        float4 v1 = *(const float4*)(Wsrc + (size_t)h * 256 + d0 + 4);
        half8 hv;
        hv[0] = (_Float16)v0.x; hv[1] = (_Float16)v0.y;
        hv[2] = (_Float16)v0.z; hv[3] = (_Float16)v0.w;
        hv[4] = (_Float16)v1.x; hv[5] = (_Float16)v1.y;
        hv[6] = (_Float16)v1.z; hv[7] = (_Float16)v1.w;
        const int db = d0 >> 5, dq = (d0 >> 3) & 3;
        size_t off = (size_t)z * 32768 +
                     ((size_t)((h >> 4) * 8 + db)) * 512 + dq * 128 + (h & 15) * 8;
        *(half8*)(Wf + off) = hv;
    }
}

// ---------------------------------------------------------------------------
// MFMA projections (unchanged): pq/pk fp16 packed.
// ---------------------------------------------------------------------------
__launch_bounds__(256, 2)
__global__ void proj_mfma_kernel(const float* __restrict__ queries,
                                 const float* __restrict__ keys,
                                 const _Float16* __restrict__ Wf,
                                 const float* __restrict__ scaling,
                                 _Float16* __restrict__ pqo,
                                 _Float16* __restrict__ pko) {
    const int t = threadIdx.x;
    const int w = t >> 6;
    const int lane = t & 63;
    const int l15 = lane & 15;
    const int quad = lane >> 4;
    const int z = blockIdx.z;
    const int half = blockIdx.y;
    const int r0 = blockIdx.x * 64;
    const float* in = z ? keys : queries;
    _Float16* outp = z ? pko : pqo;

    __shared__ __attribute__((aligned(16))) _Float16 Wl[32 * 512];
    __shared__ __attribute__((aligned(16))) _Float16 Af[4][8 * 512];

    {
        const _Float16* wsrc = Wf + ((size_t)z * 64 + half * 32) * 512;
#pragma unroll
        for (int i = 0; i < 8; ++i) {
            const int f = w * 8 + i;
            __builtin_amdgcn_global_load_lds(
                (const __attribute__((address_space(1))) uint*)(wsrc + f * 512 + lane * 8),
                (__attribute__((address_space(3))) uint*)(Wl + f * 512 + lane * 8),
                16, 0, 0);
        }
    }
    {
#pragma unroll
        for (int j = 0; j < 16; ++j) {
            const int idx = t + 256 * j;
            const int row = idx >> 6;
            const int c4 = idx & 63;
            float4 v = *(const float4*)(in + ((size_t)(r0 + row)) * 256 + c4 * 4);
            half4t h4;
            h4[0] = (_Float16)v.x; h4[1] = (_Float16)v.y;
            h4[2] = (_Float16)v.z; h4[3] = (_Float16)v.w;
            const int rt = row >> 4, rl = row & 15;
            const int d0 = c4 * 4;
            const int db = d0 >> 5, dq = (d0 >> 3) & 3, e = d0 & 7;
            *(half4t*)(&Af[rt][db * 512 + dq * 128 + rl * 8 + e]) = h4;
        }
    }
    __syncthreads();

    half8 a[8];
#pragma unroll
    for (int db = 0; db < 8; ++db)
        a[db] = *(const half8*)(&Af[w][db * 512 + lane * 8]);

    f32x4 acc[4];
#pragma unroll
    for (int hti = 0; hti < 4; ++hti) acc[hti] = (f32x4){0.f, 0.f, 0.f, 0.f};
#pragma unroll
    for (int db = 0; db < 8; ++db)
#pragma unroll
        for (int hti = 0; hti < 4; ++hti) {
            half8 bfrag = *(const half8*)(Wl + (hti * 8 + db) * 512 + lane * 8);
            acc[hti] = __builtin_amdgcn_mfma_f32_16x16x32_f16(a[db], bfrag, acc[hti], 0, 0, 0);
        }

    _Float16* S = Af[w];
#pragma unroll
    for (int hti = 0; hti < 4; ++hti) {
        const int hl_ = hti * 16 + l15;
        const int hb = hl_ >> 5, hq = (hl_ >> 3) & 3, e = hl_ & 7;
        const float scl = z ? scaling[half * 64 + hl_] : 1.f;
#pragma unroll
        for (int r = 0; r < 4; ++r) {
            float v = fmaxf(acc[hti][r], 0.f) * scl;
            S[hb * 512 + hq * 128 + (quad * 4 + r) * 8 + e] = (_Float16)v;
        }
    }
    const size_t grow16 = (size_t)(r0 >> 4) + w;
    _Float16* gout = outp + (grow16 * 4 + half * 2) * 512;
#pragma unroll
    for (int hb = 0; hb < 2; ++hb) {
        half8 vv = *(const half8*)(S + hb * 512 + lane * 8);
        *(half8*)(gout + hb * 512 + lane * 8) = vv;
    }
}

// ---------------------------------------------------------------------------
// V -> fp16 packed fragment layout (unchanged).
// ---------------------------------------------------------------------------
__global__ void vtrans_kernel(const float* __restrict__ v1,
                              const float* __restrict__ v2,
                              _Float16* __restrict__ vt1,
                              _Float16* __restrict__ vt2) {
    const int t = threadIdx.x;
    const int zz = blockIdx.z;
    const int b = zz & 7;
    const int which = zz >> 3;
    const float* src = (which ? v2 : v1) + (size_t)b * L * D;
    _Float16* dst = which ? vt2 : vt1;
    const int k0 = blockIdx.x * 64;
    const int d0 = blockIdx.y * 64;
    __shared__ float lt[64][65];
#pragma unroll
    for (int p = 0; p < 4; ++p) {
        int kr = p * 16 + (t >> 4);
        float4 v = *(const float4*)(src + (size_t)(k0 + kr) * D + d0 + (t & 15) * 4);
        lt[(t & 15) * 4 + 0][kr] = v.x;
        lt[(t & 15) * 4 + 1][kr] = v.y;
        lt[(t & 15) * 4 + 2][kr] = v.z;
        lt[(t & 15) * 4 + 3][kr] = v.w;
    }
    __syncthreads();
    const int d = t & 63;
    const int kk = (t >> 6) & 1;
    const int qp = t >> 7;
    const size_t tile = ((size_t)b * L + k0) / 32 + kk;
    const int ct = (d0 + d) >> 4;
    _Float16* base = dst + (tile * 16 + ct) * 512 + (d & 15) * 8;
#pragma unroll
    for (int s = 0; s < 2; ++s) {
        const int qv = qp * 2 + s;
        const float* lr = &lt[d][kk * 32 + qv * 8];
        half8 hv;
#pragma unroll
        for (int e = 0; e < 8; ++e) hv[e] = (_Float16)lr[e];
        *(half8*)(base + qv * 128) = hv;
    }
}

// ---------------------------------------------------------------------------
// attn_fused v2: D split across blocks. Block = 64 rows x 128 d (4 waves x
// 16 rows), key-tiles of 32, double-buffered LDS (K 8 KB + V-half 8 KB per
// tile; 36 KB total incl. P-bounce) -> 4 blocks/CU, 16 waves/CU.
// S^T = mfma(Kfrag, Qfrag); P^T B-frag via 1 KB per-wave LDS bounce.
// Online softmax with defer-max THR=8. Grid (L/64, B, 4), block 256.
// ---------------------------------------------------------------------------
__launch_bounds__(256, 4)
__global__ void attn_fused_kernel(const _Float16* __restrict__ pqw,
                                  const _Float16* __restrict__ pkw,
                                  const float* __restrict__ fb1,
                                  const float* __restrict__ fb2,
                                  const _Float16* __restrict__ vt1,
                                  const _Float16* __restrict__ vt2,
                                  float* __restrict__ out) {
    const int t = threadIdx.x;
    const int w = t >> 6;
    const int lane = t & 63;
    const int l15 = lane & 15;
    const int quad = lane >> 4;
    const int bb = blockIdx.y;
    const int zz = blockIdx.z;
    const int z = zz >> 1;        // branch
    const int dh = zz & 1;        // d-half (128 cols)
    const int r0 = blockIdx.x * 64;
    const size_t bL = (size_t)bb * L;

    const _Float16* Qp = z ? pkw : pqw;   // rows side
    const _Float16* Kp = z ? pqw : pkw;   // inner (reduction) side
    const _Float16* Vp = z ? vt2 : vt1;
    const float* fbb = (z ? fb2 : fb1) + bL;
    float* O = out + (z ? (size_t)B * L * D : 0);

    __shared__ __attribute__((aligned(16))) _Float16 klds[2][4096];   // 16 KB
    __shared__ __attribute__((aligned(16))) _Float16 vlds[2][4096];   // 16 KB
    __shared__ __attribute__((aligned(16))) _Float16 plds[4][512];    //  4 KB

    // stage one 32-key tile: K-frags (full H) + V-frags (this d-half only).
    // 16 loads/block = 4/wave.
    auto stage = [&](int it, int buf) {
        const _Float16* ksrc = Kp + ((bL + it * 32) >> 4) * 2048;
#pragma unroll
        for (int i = 0; i < 2; ++i) {
            const int c = w * 2 + i;
            __builtin_amdgcn_global_load_lds(
                (const __attribute__((address_space(1))) uint*)(ksrc + c * 512 + lane * 8),
                (__attribute__((address_space(3))) uint*)(&klds[buf][c * 512] + lane * 8),
                16, 0, 0);
        }
        const _Float16* vsrc = Vp + ((bL + it * 32) >> 5) * (size_t)8192;
#pragma unroll
        for (int i = 0; i < 2; ++i) {
            const int c = w * 2 + i;   // 0..7 within this d-half
            __builtin_amdgcn_global_load_lds(
                (const __attribute__((address_space(1))) uint*)(vsrc + (dh * 8 + c) * 512 + lane * 8),
                (__attribute__((address_space(3))) uint*)(&vlds[buf][c * 512] + lane * 8),
                16, 0, 0);
        }
    };

    // Q fragments for this wave's 16 rows (rows r0+w*16 .. +15)
    half8 aq[4];
    {
        const _Float16* qb = Qp + ((bL + r0 + w * 16) >> 4) * 2048 + lane * 8;
#pragma unroll
        for (int hb = 0; hb < 4; ++hb) aq[hb] = *(const half8*)(qb + hb * 512);
    }

    stage(0, 0);
    // bias for tile 0 (key = quad*4+r of mt0 / mt1)
    float4 bc0 = *(const float4*)(fbb + quad * 4);
    float4 bc1 = *(const float4*)(fbb + 16 + quad * 4);
    stage(1, 1);

    asm volatile("s_waitcnt vmcnt(4)" ::: "memory");
    __builtin_amdgcn_sched_barrier(0);
    __builtin_amdgcn_s_barrier();
    __builtin_amdgcn_sched_barrier(0);

    f32x4 acc[8];
#pragma unroll
    for (int ct = 0; ct < 8; ++ct) acc[ct] = (f32x4){0.f, 0.f, 0.f, 0.f};
    float lsum = 0.f;
    float m = -1e30f;

    const int NT = 64;
#pragma unroll 2
    for (int it = 0; it < NT; ++it) {
        const int buf = it & 1;

        // prefetch next tile's bias into regs
        float4 bn0 = bc0, bn1 = bc1;
        if (it + 1 < NT) {
            bn0 = *(const float4*)(fbb + (it + 1) * 32 + quad * 4);
            bn1 = *(const float4*)(fbb + (it + 1) * 32 + 16 + quad * 4);
        }

        // S^T = K-tile x Q: s[mt][r] = S^T[key=mt*16+quad*4+r][q=l15]
        f32x4 s0 = (f32x4){0.f, 0.f, 0.f, 0.f};
        f32x4 s1 = (f32x4){0.f, 0.f, 0.f, 0.f};
#pragma unroll
        for (int hb = 0; hb < 4; ++hb) {
            half8 kf0 = *(const half8*)(&klds[buf][hb * 512 + lane * 8]);
            half8 kf1 = *(const half8*)(&klds[buf][2048 + hb * 512 + lane * 8]);
            s0 = __builtin_amdgcn_mfma_f32_16x16x32_f16(kf0, aq[hb], s0, 0, 0, 0);
            s1 = __builtin_amdgcn_mfma_f32_16x16x32_f16(kf1, aq[hb], s1, 0, 0, 0);
        }
        // bias + tile max (row = q = l15; reduce over quads)
        float sv0[4], sv1[4];
        float mt_ = -INFINITY;
#pragma unroll
        for (int r = 0; r < 4; ++r) {
            sv0[r] = s0[r] + ((const float*)&bc0)[r];
            sv1[r] = s1[r] + ((const float*)&bc1)[r];
            mt_ = fmaxf(mt_, fmaxf(sv0[r], sv1[r]));
        }
        mt_ = fmaxf(mt_, __shfl_xor(mt_, 16));
        mt_ = fmaxf(mt_, __shfl_xor(mt_, 32));

        // online max with defer threshold 8 (rescale rare)
        if (!__all(mt_ <= m + 8.f)) {
            float mn = fmaxf(m, mt_);
            float sc = __expf(m - mn);
            m = mn;
            lsum *= sc;
#pragma unroll
            for (int ct = 0; ct < 8; ++ct) acc[ct] *= sc;
        }

        // P = exp(s - m), partial row sum, pack fp16
        float psum = 0.f;
        float p0[4], p1[4];
#pragma unroll
        for (int r = 0; r < 4; ++r) {
            p0[r] = __expf(sv0[r] - m);
            p1[r] = __expf(sv1[r] - m);
            psum += p0[r] + p1[r];
        }
        lsum += psum;
        half2v q00; q00[0] = (_Float16)p0[0]; q00[1] = (_Float16)p0[1];
        half2v q01; q01[0] = (_Float16)p0[2]; q01[1] = (_Float16)p0[3];
        half2v q10; q10[0] = (_Float16)p1[0]; q10[1] = (_Float16)p1[1];
        half2v q11; q11[0] = (_Float16)p1[2]; q11[1] = (_Float16)p1[3];
        // bounce P^T into B-frag layout: elem(key,q) = (key>>3)*128 + q*8 + (key&7)
        _Float16* pw = &plds[w][0];
        const int eb0 = (quad >> 1) * 128 + l15 * 8 + (quad & 1) * 4;
        const int eb1 = (2 + (quad >> 1)) * 128 + l15 * 8 + (quad & 1) * 4;
        *(half2v*)(pw + eb0) = q00;
        *(half2v*)(pw + eb0 + 2) = q01;
        *(half2v*)(pw + eb1) = q10;
        *(half2v*)(pw + eb1 + 2) = q11;
        half8 pfrag = *(const half8*)(pw + lane * 8);   // wave-local RAW, lgkmcnt by compiler

        // PV: out^T[d][q] += V^T x P^T  (A = V-frag direct from vt layout)
#pragma unroll
        for (int ct = 0; ct < 8; ++ct) {
            half8 vf = *(const half8*)(&vlds[buf][ct * 512 + lane * 8]);
            acc[ct] = __builtin_amdgcn_mfma_f32_16x16x32_f16(vf, pfrag, acc[ct], 0, 0, 0);
        }

        bc0 = bn0; bc1 = bn1;

        if (it < NT - 1) {
            // release buf (all waves finished reading it)
            __builtin_amdgcn_s_barrier();
            __builtin_amdgcn_sched_barrier(0);
            if (it + 2 < NT) {
                stage(it + 2, buf);
                // tile it+1 landed (4 newest outstanding = tile it+2)
                asm volatile("s_waitcnt vmcnt(4)" ::: "memory");
            } else {
                asm volatile("s_waitcnt vmcnt(0)" ::: "memory");
            }
            __builtin_amdgcn_sched_barrier(0);
            __builtin_amdgcn_s_barrier();
            __builtin_amdgcn_sched_barrier(0);
        }
    }

    // finish softmax denom: reduce across quads (row = l15)
    lsum += __shfl_xor(lsum, 16);
    lsum += __shfl_xor(lsum, 32);
    const float inv = (lsum > 0.f) ? (1.f / lsum) : 0.f;

    // store: lane holds out[q=r0+w*16+l15][d=dh*128+ct*16+quad*4+r]
    const int qrow = r0 + w * 16 + l15;
    float* orow = O + (bL + qrow) * (size_t)D + dh * 128 + quad * 4;
#pragma unroll
    for (int ct = 0; ct < 8; ++ct) {
        f32x4 v = acc[ct] * inv;
        *(f32x4*)(orow + ct * 16) = v;
    }
}

extern "C" void kernel_launch(void* const* d_in, const int* in_sizes, int n_in,
                              void* d_out, int out_size, void* d_ws, size_t ws_size,
                              hipStream_t stream) {
    const float* queries  = (const float*)d_in[0];
    const float* keys     = (const float*)d_in[1];
    const float* values_1 = (const float*)d_in[2];
    const void*  v1_mask  = d_in[3];
    const float* values_2 = (const float*)d_in[4];
    const void*  v2_mask  = d_in[5];
    const float* Wq       = (const float*)d_in[6];
    const float* Wk       = (const float*)d_in[7];
    const float* scaling  = (const float*)d_in[8];
    float* out = (float*)d_out;

    _Float16* pqw = (_Float16*)d_ws;                       // B*L*H   (4 MB)
    _Float16* pkw = pqw + (size_t)B * L * H;               // 4 MB
    _Float16* vt1 = pkw + (size_t)B * L * H;               // B*L*D   (8 MB)
    _Float16* vt2 = vt1 + (size_t)B * L * D;               // 8 MB
    float* fb1   = (float*)(vt2 + (size_t)B * L * D);      // 64 KB
    float* fb2   = fb1 + B * L;                            // 64 KB
    _Float16* Wf = (_Float16*)(fb2 + B * L);               // 128 KB

    prep_kernel<<<dim3(16, 2), 256, 0, stream>>>(
        v1_mask, v2_mask, Wq, Wk, fb1, fb2, Wf);
    proj_mfma_kernel<<<dim3(B * L / 64, 2, 2), 256, 0, stream>>>(
        queries, keys, Wf, scaling, pqw, pkw);
    vtrans_kernel<<<dim3(L / 64, D / 64, B * 2), 256, 0, stream>>>(
        values_1, values_2, vt1, vt2);
    attn_fused_kernel<<<dim3(L / 64, B, 4), 256, 0, stream>>>(
        pqw, pkw, fb1, fb2, vt1, vt2, out);
}

// Round 10
// 223.211 us; speedup vs baseline: 1.1664x; 1.1664x over previous
//
#include <hip/hip_runtime.h>
#include <cstdint>
#include <math.h>

#define B 8
#define L 2048
#define D 256
#define H 128

typedef __attribute__((ext_vector_type(8))) _Float16 half8;
typedef __attribute__((ext_vector_type(4))) _Float16 half4t;
typedef __attribute__((ext_vector_type(2))) _Float16 half2v;
typedef __attribute__((ext_vector_type(4))) float f32x4;
typedef unsigned short ushort;
typedef unsigned int uint;

// Layouts:
//  pq/pk (B*L*H fp16) packed MFMA-frag blocks: block=(grow/16)*4+h/32,
//     elem=((h>>3)&3)*128+(grow&15)*8+(h&7)   [proven R4-R6]
//  vt (B*L*D fp16): block=((b*L+key)/32)*16+d/16, elem=((key&31)>>3)*128+(d&15)*8+(key&7)
// R10: fused pre-kernel, FIXED vtrans block count (2048, was 1024 in R9 ->
// vt2 never written -> branch-2 garbage). Dispatch: bid%3==0 -> proj (1024),
// bid%3 in {1,2} -> vtrans (2048), bid>=3072 -> mask (32). attn_fused = R6
// exact (proven 113us).
// ---------------------------------------------------------------------------
__launch_bounds__(256, 2)
__global__ void pre_kernel(const float* __restrict__ queries,
                           const float* __restrict__ keys,
                           const float* __restrict__ Wq,
                           const float* __restrict__ Wk,
                           const float* __restrict__ scaling,
                           const void* __restrict__ raw0,
                           const void* __restrict__ raw1,
                           const float* __restrict__ v1,
                           const float* __restrict__ v2,
                           _Float16* __restrict__ pqo,
                           _Float16* __restrict__ pko,
                           _Float16* __restrict__ vt1,
                           _Float16* __restrict__ vt2,
                           float* __restrict__ fb1,
                           float* __restrict__ fb2) {
    __shared__ __attribute__((aligned(16))) union {
        struct { _Float16 Wl[32 * 512]; _Float16 Af[4][8 * 512]; } proj;  // 64 KB
        float lt[64][65];                                                  // 16.6 KB
    } sh;
    __shared__ int flag;

    const int bid = blockIdx.x;
    const int t = threadIdx.x;

    if (bid < 3072 && (bid % 3) == 0) {
        // ----------------- proj role: idx in [0,1024) -----------------
        const int idx = bid / 3;
        const int w = t >> 6;
        const int lane = t & 63;
        const int l15 = lane & 15;
        const int quad = lane >> 4;
        const int z = idx >> 9;
        const int half = (idx >> 8) & 1;
        const int r0 = (idx & 255) * 64;
        const float* in = z ? keys : queries;
        const float* Wsrc = z ? Wk : Wq;
        _Float16* outp = z ? pko : pqo;
        _Float16* Wl = sh.proj.Wl;

        // inline W pack: rows h = half*64 .. +63, 2048 chunks, 8/thread
#pragma unroll
        for (int i = 0; i < 8; ++i) {
            const int cl = t + 256 * i;
            const int hl = cl >> 5;            // 0..63
            const int d0 = (cl & 31) * 8;
            const float* wp = Wsrc + (size_t)(half * 64 + hl) * 256 + d0;
            float4 v0 = *(const float4*)wp;
            float4 v1w = *(const float4*)(wp + 4);
            half8 hv;
            hv[0] = (_Float16)v0.x; hv[1] = (_Float16)v0.y;
            hv[2] = (_Float16)v0.z; hv[3] = (_Float16)v0.w;
            hv[4] = (_Float16)v1w.x; hv[5] = (_Float16)v1w.y;
            hv[6] = (_Float16)v1w.z; hv[7] = (_Float16)v1w.w;
            const int db = d0 >> 5, dq = (d0 >> 3) & 3;
            *(half8*)(Wl + ((hl >> 4) * 8 + db) * 512 + dq * 128 + (hl & 15) * 8) = hv;
        }
        // A staging (64 rows x 256 cols fp32 -> packed fp16 frags)
#pragma unroll
        for (int j = 0; j < 16; ++j) {
            const int idx2 = t + 256 * j;
            const int row = idx2 >> 6;
            const int c4 = idx2 & 63;
            float4 v = *(const float4*)(in + ((size_t)(r0 + row)) * 256 + c4 * 4);
            half4t h4;
            h4[0] = (_Float16)v.x; h4[1] = (_Float16)v.y;
            h4[2] = (_Float16)v.z; h4[3] = (_Float16)v.w;
            const int rt = row >> 4, rl = row & 15;
            const int d0 = c4 * 4;
            const int db = d0 >> 5, dq = (d0 >> 3) & 3, e = d0 & 7;
            *(half4t*)(&sh.proj.Af[rt][db * 512 + dq * 128 + rl * 8 + e]) = h4;
        }
        __syncthreads();

        half8 a[8];
#pragma unroll
        for (int db = 0; db < 8; ++db)
            a[db] = *(const half8*)(&sh.proj.Af[w][db * 512 + lane * 8]);

        f32x4 acc[4];
#pragma unroll
        for (int hti = 0; hti < 4; ++hti) acc[hti] = (f32x4){0.f, 0.f, 0.f, 0.f};
#pragma unroll
        for (int db = 0; db < 8; ++db)
#pragma unroll
            for (int hti = 0; hti < 4; ++hti) {
                half8 bfrag = *(const half8*)(Wl + (hti * 8 + db) * 512 + lane * 8);
                acc[hti] = __builtin_amdgcn_mfma_f32_16x16x32_f16(a[db], bfrag, acc[hti], 0, 0, 0);
            }

        _Float16* S = sh.proj.Af[w];
#pragma unroll
        for (int hti = 0; hti < 4; ++hti) {
            const int hl_ = hti * 16 + l15;
            const int hb = hl_ >> 5, hq = (hl_ >> 3) & 3, e = hl_ & 7;
            const float scl = z ? scaling[half * 64 + hl_] : 1.f;
#pragma unroll
            for (int r = 0; r < 4; ++r) {
                float v = fmaxf(acc[hti][r], 0.f) * scl;
                S[hb * 512 + hq * 128 + (quad * 4 + r) * 8 + e] = (_Float16)v;
            }
        }
        const size_t grow16 = (size_t)(r0 >> 4) + w;
        _Float16* gout = outp + (grow16 * 4 + half * 2) * 512;
#pragma unroll
        for (int hb = 0; hb < 2; ++hb) {
            half8 vv = *(const half8*)(S + hb * 512 + lane * 8);
            *(half8*)(gout + hb * 512 + lane * 8) = vv;
        }
    } else if (bid < 3072) {
        // ----------------- vtrans role: idx in [0,2048) -----------------
        const int idx = (bid / 3) * 2 + (bid % 3) - 1;
        const int zz = idx >> 7;          // 0..15: b = zz&7, which = zz>>3
        const int b = zz & 7;
        const int which = zz >> 3;
        const int x = idx & 31;
        const int y = (idx >> 5) & 3;
        const float* src = (which ? v2 : v1) + (size_t)b * L * D;
        _Float16* dst = which ? vt2 : vt1;
        const int k0 = x * 64;
        const int d0 = y * 64;
#pragma unroll
        for (int p = 0; p < 4; ++p) {
            int kr = p * 16 + (t >> 4);
            float4 v = *(const float4*)(src + (size_t)(k0 + kr) * D + d0 + (t & 15) * 4);
            sh.lt[(t & 15) * 4 + 0][kr] = v.x;
            sh.lt[(t & 15) * 4 + 1][kr] = v.y;
            sh.lt[(t & 15) * 4 + 2][kr] = v.z;
            sh.lt[(t & 15) * 4 + 3][kr] = v.w;
        }
        __syncthreads();
        const int d = t & 63;
        const int kk = (t >> 6) & 1;
        const int qp = t >> 7;
        const size_t tile = ((size_t)b * L + k0) / 32 + kk;
        const int ct = (d0 + d) >> 4;
        _Float16* base = dst + (tile * 16 + ct) * 512 + (d & 15) * 8;
#pragma unroll
        for (int s = 0; s < 2; ++s) {
            const int qv = qp * 2 + s;
            const float* lr = &sh.lt[d][kk * 32 + qv * 8];
            half8 hv;
#pragma unroll
            for (int e = 0; e < 8; ++e) hv[e] = (_Float16)lr[e];
            *(half8*)(base + qv * 128) = hv;
        }
    } else {
        // ----------------- mask->bias role: idx in [0,32) -----------------
        const int idx = bid - 3072;
        const int x = idx & 15;
        const int z = idx >> 4;
        const void* raw = z ? raw1 : raw0;
        float* outb = z ? fb2 : fb1;
        const uint* wd = (const uint*)raw;
        if (t == 0) flag = 0;
        __syncthreads();
        if (wd[t] > 1u) flag = 1;   // byte-bool layout iff some word >1
        __syncthreads();
        const int base = x * 1024;
        if (flag) {
            const uint8_t* by = (const uint8_t*)raw;
#pragma unroll
            for (int j = 0; j < 4; ++j) {
                int i = base + t + 256 * j;
                outb[i] = by[i] ? -INFINITY : 0.f;
            }
        } else {
#pragma unroll
            for (int j = 0; j < 4; ++j) {
                int i = base + t + 256 * j;
                outb[i] = wd[i] ? -INFINITY : 0.f;
            }
        }
    }
}

// ---------------------------------------------------------------------------
// attn_fused (R6 exact, proven 113us): score + online softmax + PV, one pass.
// Block = 64 out-rows (4 waves x 16), key-tiles of 32, double-buffered LDS.
// Grid (L/64, B, 2), block 256.
// ---------------------------------------------------------------------------
__launch_bounds__(256, 2)
__global__ void attn_fused_kernel(const _Float16* __restrict__ pqw,
                                  const _Float16* __restrict__ pkw,
                                  const float* __restrict__ fb1,
                                  const float* __restrict__ fb2,
                                  const _Float16* __restrict__ vt1,
                                  const _Float16* __restrict__ vt2,
                                  float* __restrict__ out) {
    const int t = threadIdx.x;
    const int w = t >> 6;
    const int lane = t & 63;
    const int l15 = lane & 15;
    const int quad = lane >> 4;
    const int bb = blockIdx.y;
    const int z = blockIdx.z;
    const int r0 = blockIdx.x * 64;
    const size_t bL = (size_t)bb * L;

    const _Float16* Qp = z ? pkw : pqw;   // rows side
    const _Float16* Kp = z ? pqw : pkw;   // inner (reduction) side
    const _Float16* Vp = z ? vt2 : vt1;
    const float* fbb = (z ? fb2 : fb1) + bL;
    float* O = out + (z ? (size_t)B * L * D : 0);

    __shared__ __attribute__((aligned(16))) _Float16 klds[2][4096];   // 16 KB
    __shared__ __attribute__((aligned(16))) _Float16 vlds[2][8192];   // 32 KB
    __shared__ __attribute__((aligned(16))) _Float16 plds[4][512];    //  4 KB

    auto stage = [&](int it, int buf) {
        const _Float16* ksrc = Kp + ((bL + it * 32) >> 4) * 2048;
#pragma unroll
        for (int i = 0; i < 2; ++i) {
            const int c = w * 2 + i;
            __builtin_amdgcn_global_load_lds(
                (const __attribute__((address_space(1))) uint*)(ksrc + c * 512 + lane * 8),
                (__attribute__((address_space(3))) uint*)(&klds[buf][c * 512] + lane * 8),
                16, 0, 0);
        }
        const _Float16* vsrc = Vp + ((bL + it * 32) >> 5) * (size_t)8192;
#pragma unroll
        for (int i = 0; i < 4; ++i) {
            const int c = w * 4 + i;
            __builtin_amdgcn_global_load_lds(
                (const __attribute__((address_space(1))) uint*)(vsrc + c * 512 + lane * 8),
                (__attribute__((address_space(3))) uint*)(&vlds[buf][c * 512] + lane * 8),
                16, 0, 0);
        }
    };

    // Q fragments for this wave's 16 rows (rows r0+w*16 .. +15)
    half8 aq[4];
    {
        const _Float16* qb = Qp + ((bL + r0 + w * 16) >> 4) * 2048 + lane * 8;
#pragma unroll
        for (int hb = 0; hb < 4; ++hb) aq[hb] = *(const half8*)(qb + hb * 512);
    }

    stage(0, 0);
    float4 bc0 = *(const float4*)(fbb + quad * 4);
    float4 bc1 = *(const float4*)(fbb + 16 + quad * 4);
    stage(1, 1);

    asm volatile("s_waitcnt vmcnt(6)" ::: "memory");
    __builtin_amdgcn_sched_barrier(0);
    __builtin_amdgcn_s_barrier();
    __builtin_amdgcn_sched_barrier(0);

    f32x4 acc[16];
#pragma unroll
    for (int ct = 0; ct < 16; ++ct) acc[ct] = (f32x4){0.f, 0.f, 0.f, 0.f};
    float lsum = 0.f;
    float m = -1e30f;

    const int NT = 64;
#pragma unroll 2
    for (int it = 0; it < NT; ++it) {
        const int buf = it & 1;

        float4 bn0 = bc0, bn1 = bc1;
        if (it + 1 < NT) {
            bn0 = *(const float4*)(fbb + (it + 1) * 32 + quad * 4);
            bn1 = *(const float4*)(fbb + (it + 1) * 32 + 16 + quad * 4);
        }

        // S^T = K-tile x Q: s[mt][r] = S^T[key=mt*16+quad*4+r][q=l15]
        f32x4 s0 = (f32x4){0.f, 0.f, 0.f, 0.f};
        f32x4 s1 = (f32x4){0.f, 0.f, 0.f, 0.f};
#pragma unroll
        for (int hb = 0; hb < 4; ++hb) {
            half8 kf0 = *(const half8*)(&klds[buf][hb * 512 + lane * 8]);
            half8 kf1 = *(const half8*)(&klds[buf][2048 + hb * 512 + lane * 8]);
            s0 = __builtin_amdgcn_mfma_f32_16x16x32_f16(kf0, aq[hb], s0, 0, 0, 0);
            s1 = __builtin_amdgcn_mfma_f32_16x16x32_f16(kf1, aq[hb], s1, 0, 0, 0);
        }
        float sv0[4], sv1[4];
        float mt_ = -INFINITY;
#pragma unroll
        for (int r = 0; r < 4; ++r) {
            sv0[r] = s0[r] + ((const float*)&bc0)[r];
            sv1[r] = s1[r] + ((const float*)&bc1)[r];
            mt_ = fmaxf(mt_, fmaxf(sv0[r], sv1[r]));
        }
        mt_ = fmaxf(mt_, __shfl_xor(mt_, 16));
        mt_ = fmaxf(mt_, __shfl_xor(mt_, 32));

        if (!__all(mt_ <= m + 8.f)) {
            float mn = fmaxf(m, mt_);
            float sc = __expf(m - mn);
            m = mn;
            lsum *= sc;
#pragma unroll
            for (int ct = 0; ct < 16; ++ct) acc[ct] *= sc;
        }

        float psum = 0.f;
        float p0[4], p1[4];
#pragma unroll
        for (int r = 0; r < 4; ++r) {
            p0[r] = __expf(sv0[r] - m);
            p1[r] = __expf(sv1[r] - m);
            psum += p0[r] + p1[r];
        }
        lsum += psum;
        half2v q00; q00[0] = (_Float16)p0[0]; q00[1] = (_Float16)p0[1];
        half2v q01; q01[0] = (_Float16)p0[2]; q01[1] = (_Float16)p0[3];
        half2v q10; q10[0] = (_Float16)p1[0]; q10[1] = (_Float16)p1[1];
        half2v q11; q11[0] = (_Float16)p1[2]; q11[1] = (_Float16)p1[3];
        _Float16* pw = &plds[w][0];
        const int eb0 = (quad >> 1) * 128 + l15 * 8 + (quad & 1) * 4;
        const int eb1 = (2 + (quad >> 1)) * 128 + l15 * 8 + (quad & 1) * 4;
        *(half2v*)(pw + eb0) = q00;
        *(half2v*)(pw + eb0 + 2) = q01;
        *(half2v*)(pw + eb1) = q10;
        *(half2v*)(pw + eb1 + 2) = q11;
        half8 pfrag = *(const half8*)(pw + lane * 8);   // wave-local RAW

        // PV: out^T[d][q] += V^T x P^T
#pragma unroll
        for (int ct = 0; ct < 16; ++ct) {
            half8 vf = *(const half8*)(&vlds[buf][ct * 512 + lane * 8]);
            acc[ct] = __builtin_amdgcn_mfma_f32_16x16x32_f16(vf, pfrag, acc[ct], 0, 0, 0);
        }

        bc0 = bn0; bc1 = bn1;

        if (it < NT - 1) {
            __builtin_amdgcn_s_barrier();
            __builtin_amdgcn_sched_barrier(0);
            if (it + 2 < NT) {
                stage(it + 2, buf);
                asm volatile("s_waitcnt vmcnt(6)" ::: "memory");
            } else {
                asm volatile("s_waitcnt vmcnt(0)" ::: "memory");
            }
            __builtin_amdgcn_sched_barrier(0);
            __builtin_amdgcn_s_barrier();
            __builtin_amdgcn_sched_barrier(0);
        }
    }

    lsum += __shfl_xor(lsum, 16);
    lsum += __shfl_xor(lsum, 32);
    const float inv = (lsum > 0.f) ? (1.f / lsum) : 0.f;

    const int qrow = r0 + w * 16 + l15;
    float* orow = O + (bL + qrow) * (size_t)D + quad * 4;
#pragma unroll
    for (int ct = 0; ct < 16; ++ct) {
        f32x4 v = acc[ct] * inv;
        *(f32x4*)(orow + ct * 16) = v;
    }
}

extern "C" void kernel_launch(void* const* d_in, const int* in_sizes, int n_in,
                              void* d_out, int out_size, void* d_ws, size_t ws_size,
                              hipStream_t stream) {
    const float* queries  = (const float*)d_in[0];
    const float* keys     = (const float*)d_in[1];
    const float* values_1 = (const float*)d_in[2];
    const void*  v1_mask  = d_in[3];
    const float* values_2 = (const float*)d_in[4];
    const void*  v2_mask  = d_in[5];
    const float* Wq       = (const float*)d_in[6];
    const float* Wk       = (const float*)d_in[7];
    const float* scaling  = (const float*)d_in[8];
    float* out = (float*)d_out;

    _Float16* pqw = (_Float16*)d_ws;                       // B*L*H   (4 MB)
    _Float16* pkw = pqw + (size_t)B * L * H;               // 4 MB
    _Float16* vt1 = pkw + (size_t)B * L * H;               // B*L*D   (8 MB)
    _Float16* vt2 = vt1 + (size_t)B * L * D;               // 8 MB
    float* fb1   = (float*)(vt2 + (size_t)B * L * D);      // 64 KB
    float* fb2   = fb1 + B * L;                            // 64 KB

    pre_kernel<<<3104, 256, 0, stream>>>(
        queries, keys, Wq, Wk, scaling, v1_mask, v2_mask,
        values_1, values_2, pqw, pkw, vt1, vt2, fb1, fb2);
    attn_fused_kernel<<<dim3(L / 64, B, 2), 256, 0, stream>>>(
        pqw, pkw, fb1, fb2, vt1, vt2, out);
}